// Round 2
// baseline (52.753 us; speedup 1.0000x reference)
//
#include <hip/hip_runtime.h>

#define UNITS 4096
#define BATCH 8192

// out[b,j] = x[b,j] * w[j,j]  (masked_w = w * I collapses to a column scale).
//
// Fused single kernel: grid-stride over float4s with stride
// gridDim*blockDim = 2048*256 = 524288, a multiple of the row width
// (UNITS/4 = 1024), so each thread's column group c = i & 1023 is
// loop-invariant. Load the 4 diagonal scalars once into registers
// (w[(4c+k)*(UNITS+1)], strided lines are L2-resident across blocks),
// then stream 16 row iterations of read*scale->write.
__global__ void __launch_bounds__(256)
diag_scale_fused_kernel(const float* __restrict__ x,
                        const float* __restrict__ w,
                        float* __restrict__ out) {
    const int n4 = (BATCH * UNITS) / 4;           // 8,388,608 float4s
    const int stride = gridDim.x * blockDim.x;    // 524288: multiple of 1024
    const float4* __restrict__ x4 = (const float4*)x;
    float4* __restrict__ o4 = (float4*)out;

    int i0 = blockIdx.x * blockDim.x + threadIdx.x;
    int c = i0 & (UNITS / 4 - 1);                 // column group, loop-invariant

    // diag[j] = w[j*UNITS + j] = w[j*(UNITS+1)]
    const size_t j0 = (size_t)(4 * c) * (UNITS + 1);
    float4 dv;
    dv.x = w[j0];
    dv.y = w[j0 + (UNITS + 1)];
    dv.z = w[j0 + 2 * (UNITS + 1)];
    dv.w = w[j0 + 3 * (UNITS + 1)];

    for (int i = i0; i < n4; i += stride) {
        float4 xv = x4[i];
        float4 ov;
        ov.x = xv.x * dv.x;
        ov.y = xv.y * dv.y;
        ov.z = xv.z * dv.z;
        ov.w = xv.w * dv.w;
        o4[i] = ov;
    }
}

extern "C" void kernel_launch(void* const* d_in, const int* in_sizes, int n_in,
                              void* d_out, int out_size, void* d_ws, size_t ws_size,
                              hipStream_t stream) {
    const float* x = (const float*)d_in[0];
    const float* w = (const float*)d_in[1];
    float* out = (float*)d_out;

    const int blocks = 2048;                      // stride 524288 = 512 rows
    diag_scale_fused_kernel<<<blocks, 256, 0, stream>>>(x, w, out);
}